// Round 9
// baseline (1691.303 us; speedup 1.0000x reference)
//
#include <hip/hip_runtime.h>

static constexpr int H = 4096;
static constexpr int W = 4096;
static constexpr long N = (long)H * W;

static constexpr int TILE = 80;
static constexpr int HALO = 20;              // one per iteration per side
static constexpr int R    = TILE + 2*HALO;   // 120 region
static constexpr int S    = R;               // row stride (halfs)
static constexpr int PS   = R * S;           // plane size (halfs) = 14400
static constexpr int CPR  = R / 8;           // 15 chunks per row
static constexpr int NCH  = R * CPR;         // 1800 half8-chunk tasks
static constexpr int NT   = 960;             // 15 waves; <=2 chunks/thread
static constexpr int GRID = 52;              // ceil(4096/80)

static constexpr float SIGMA = 14.285714285714286f;  // 1/(7*0.01)
static constexpr float INVD  = 1.0f / 1.07f;
static constexpr float TIV   = 0.01f / 1.07f;        // TAU/(1+LT)
static constexpr float CF    = 0.07f / 1.07f;        // LAMBDA*TAU/(1+LT)

typedef _Float16 half8  __attribute__((ext_vector_type(8)));
typedef _Float16 half4v __attribute__((ext_vector_type(4)));

__device__ __forceinline__ half8 splat8(float f) {
    _Float16 h = (_Float16)f;
    half8 v = {h, h, h, h, h, h, h, h};
    return v;
}
__device__ __forceinline__ half8 clamp8(half8 v) {
    v = __builtin_elementwise_min(v, splat8(1.0f));
    v = __builtin_elementwise_max(v, splat8(-1.0f));
    return v;
}

// All 20 iterations fused, TILE=80 (halo redundancy 2.25x vs 2.64x at 64),
// 15 waves x 2 blocks/CU = 30 waves/CU. LDS: xt plane, yv plane, yh-edge
// array (61.2 KB). Thread state (sigma*w, CF*img, x, yh, yv) in fp16 regs,
// all math packed fp16. BCs data-encoded (w=0 outside image / last col /
// last row); halo invalidates 1/side/iter, HALO=20 covers 20 iters;
// out-of-range halo reads land on finite always-written LDS and feed only
// cone-invalid pixels (validated rounds 4-8).
__global__ __launch_bounds__(NT, 8) void fused_pd(
    const float* __restrict__ img,
    const float* __restrict__ wg,    // (2,H,W): wg[0]=w_h, wg[N]=w_v
    float* __restrict__ out)
{
    __shared__ _Float16 lds_s[2 * PS + NCH + 2];   // 61,204 B -> 2 blocks/CU
    _Float16* __restrict__ xtp = lds_s;            // x_tilde plane
    _Float16* __restrict__ yvp = lds_s + PS;       // y vertical plane
    _Float16* __restrict__ yhe = lds_s + 2 * PS;   // yh edges: yhe[t+1] = yh[7] of chunk t

    const int tid = threadIdx.x;
    const int gi0 = blockIdx.y * TILE - HALO;
    const int gj0 = blockIdx.x * TILE - HALO;
    const bool interior = (gi0 >= 0) && (gj0 >= 0) && (gi0 + R <= H) && (gj0 + R <= W);

    const int t0 = tid, t1 = tid + NT;
    const int i0_ = t0 / CPR, i1_ = t1 / CPR;
    const int b0 = i0_ * S + (t0 - i0_ * CPR) * 8;
    const int b1 = i1_ * S + (t1 - i1_ * CPR) * 8;
    const bool act1 = (t1 < NCH);

    // packed loop constants
    const half8 kTIV  = splat8(TIV);
    const half8 kINVD = splat8(INVD);
    const half8 k15   = splat8(1.5f);
    const half8 kM05  = splat8(-0.5f);

    // persistent per-chunk register state (fp16)
    half8 wh0, wh1, wv0, wv1;   // SIGMA*w
    half8 ci0, ci1;             // CF*img
    half8 x0, x1;               // x
    half8 yh0, yh1, yv0, yv1;   // dual state

    // ---------------- load & init ----------------
    auto loadC = [&](int t, half8& whr, half8& wvr, half8& cir, half8& xr) {
        const int i  = t / CPR;
        const int j0 = (t - i * CPR) * 8;
        const int gi = gi0 + i;
        const int gj = gj0 + j0;
        float im[8], wh[8], wv[8];
        if (interior) {
            const float4* ip = reinterpret_cast<const float4*>(img + (long)gi * W + gj);
            float4 a = ip[0], b = ip[1];
            im[0]=a.x; im[1]=a.y; im[2]=a.z; im[3]=a.w;
            im[4]=b.x; im[5]=b.y; im[6]=b.z; im[7]=b.w;
            const float4* hp = reinterpret_cast<const float4*>(wg + (long)gi * W + gj);
            float4 c = hp[0], d = hp[1];
            wh[0]=c.x*SIGMA; wh[1]=c.y*SIGMA; wh[2]=c.z*SIGMA; wh[3]=c.w*SIGMA;
            wh[4]=d.x*SIGMA; wh[5]=d.y*SIGMA; wh[6]=d.z*SIGMA; wh[7]=d.w*SIGMA;
            const float4* vp = reinterpret_cast<const float4*>(wg + N + (long)gi * W + gj);
            float4 e = vp[0], f = vp[1];
            wv[0]=e.x*SIGMA; wv[1]=e.y*SIGMA; wv[2]=e.z*SIGMA; wv[3]=e.w*SIGMA;
            wv[4]=f.x*SIGMA; wv[5]=f.y*SIGMA; wv[6]=f.z*SIGMA; wv[7]=f.w*SIGMA;
        } else {
            const int gic = min(max(gi, 0), H - 1);
            const bool rowin = (gi >= 0) && (gi < H);
#pragma unroll
            for (int k = 0; k < 8; ++k) {
                const int gjk = gj + k;
                const int gjc = min(max(gjk, 0), W - 1);
                const bool inim = rowin && (gjk >= 0) && (gjk < W);
                const long o = (long)gic * W + gjc;
                im[k] = img[o];
                wh[k] = (inim && gjk < W - 1) ? SIGMA * wg[o]     : 0.0f;
                wv[k] = (inim && gi  < H - 1) ? SIGMA * wg[N + o] : 0.0f;
            }
        }
        half8 imv;
#pragma unroll
        for (int k = 0; k < 8; ++k) {
            imv[k] = (_Float16)im[k];
            whr[k] = (_Float16)wh[k];
            wvr[k] = (_Float16)wv[k];
            cir[k] = (_Float16)(CF * im[k]);
        }
        xr = imv;
        *reinterpret_cast<half8*>(xtp + i * S + j0) = imv;   // xt = img
    };
    loadC(t0, wh0, wv0, ci0, x0);
    if (act1) loadC(t1, wh1, wv1, ci1, x1);
    yh0 = splat8(0.f); yh1 = splat8(0.f);
    yv0 = splat8(0.f); yv1 = splat8(0.f);
    if (tid == 0) yhe[0] = (_Float16)0.0f;   // left edge of chunk 0
    __syncthreads();

    for (int it = 0; it < 20; ++it) {
        // -------- dual: y = clamp(y + grad(xt) * (SIGMA*w)), packed fp16 --------
        auto dualC = [&](int t, int base, half8 wh, half8 wv, half8& yh, half8& yv) {
            half8 cv = *reinterpret_cast<const half8*>(xtp + base);
            _Float16 rt = xtp[base + 8];
            half8 bv = *reinterpret_cast<const half8*>(xtp + base + S);
            half8 sh = __builtin_shufflevector(cv, cv, 1, 2, 3, 4, 5, 6, 7, 7);
            sh[7] = rt;
            yh = clamp8((sh - cv) * wh + yh);   // pk_fma
            yv = clamp8((bv - cv) * wv + yv);   // pk_fma
            *reinterpret_cast<half8*>(yvp + base) = yv;
            yhe[t + 1] = yh[7];
        };
        dualC(t0, b0, wh0, wv0, yh0, yv0);
        if (act1) dualC(t1, b1, wh1, wv1, yh1, yv1);
        __syncthreads();

        // -------- primal, packed fp16:
        //   xn = x*INVD + (TIV*dv + ci);  xt = 1.5*xn - 0.5*x --------
        auto primC = [&](int t, int base, half8 yh, half8 yv, half8 ci, half8& x) {
            _Float16 yl = yhe[t];
            half8 yva = *reinterpret_cast<const half8*>(yvp + base - S);
            half8 ysh = __builtin_shufflevector(yh, yh, 0, 0, 1, 2, 3, 4, 5, 6);
            ysh[0] = yl;
            half8 dv = (yh - ysh) + (yv - yva);
            half8 tt = dv * kTIV + ci;          // pk_fma
            half8 xn = x * kINVD + tt;          // pk_fma
            half8 xt = xn * k15 + x * kM05;     // pk_mul + pk_fma
            x = xn;
            *reinterpret_cast<half8*>(xtp + base) = xt;
        };
        primC(t0, b0, yh0, yv0, ci0, x0);
        if (act1) primC(t1, b1, yh1, yv1, ci1, x1);
        __syncthreads();
    }

    // ---------------- store center 80x80 as fp32 (guarded) ----------------
    if (tid < TILE * (TILE / 8)) {           // 800 store tasks, 8 px each
        const int r = tid / (TILE / 8);      // 0..79
        const int c = tid - r * (TILE / 8);  // 0..9
        const int gr = blockIdx.y * TILE + r;
        const int gc = blockIdx.x * TILE + c * 8;
        if (gr < H && gc < W) {
            const int base = (HALO + r) * S + HALO + c * 8;   // 8B-aligned
            half4v a = *reinterpret_cast<const half4v*>(xtp + base);
            half4v b = *reinterpret_cast<const half4v*>(xtp + base + 4);
            float4 o0 = make_float4((float)a[0], (float)a[1], (float)a[2], (float)a[3]);
            float4 o1 = make_float4((float)b[0], (float)b[1], (float)b[2], (float)b[3]);
            const long g = (long)gr * W + gc;
            *reinterpret_cast<float4*>(out + g)     = o0;
            *reinterpret_cast<float4*>(out + g + 4) = o1;
        }
    }
}

extern "C" void kernel_launch(void* const* d_in, const int* in_sizes, int n_in,
                              void* d_out, int out_size, void* d_ws, size_t ws_size,
                              hipStream_t stream) {
    const float* img = (const float*)d_in[0];   // (1,H,W)
    const float* wg  = (const float*)d_in[1];   // (2,H,W)
    float* out = (float*)d_out;

    dim3 grid(GRID, GRID);                      // 52 x 52 = 2704 blocks
    fused_pd<<<grid, dim3(NT), 0, stream>>>(img, wg, out);
}

// Round 10
// 1635.775 us; speedup vs baseline: 1.0339x; 1.0339x over previous
//
#include <hip/hip_runtime.h>

static constexpr int H = 4096;
static constexpr int W = 4096;
static constexpr long N = (long)H * W;

static constexpr int TILE = 80;
static constexpr int HALO = 20;              // one per iteration per side
static constexpr int R    = TILE + 2*HALO;   // 120 region
static constexpr int S    = R;               // row stride (halfs)
static constexpr int PS   = R * S;           // plane size (halfs) = 14400
static constexpr int CPR  = R / 8;           // 15 chunks per row
static constexpr int NCH  = R * CPR;         // 1800 half8-chunk tasks
static constexpr int NT   = 1024;            // 16 waves: 2 blocks/CU = 32 waves/CU
static constexpr int GRID = 52;              // ceil(4096/80)

static constexpr float SIGMA = 14.285714285714286f;  // 1/(7*0.01)
static constexpr float INVD  = 1.0f / 1.07f;
static constexpr float TIV   = 0.01f / 1.07f;        // TAU/(1+LT)
static constexpr float CF    = 0.07f / 1.07f;        // LAMBDA*TAU/(1+LT)

typedef _Float16 half8  __attribute__((ext_vector_type(8)));
typedef _Float16 half4v __attribute__((ext_vector_type(4)));

__device__ __forceinline__ half8 splat8(float f) {
    _Float16 h = (_Float16)f;
    half8 v = {h, h, h, h, h, h, h, h};
    return v;
}
__device__ __forceinline__ half8 clamp8(half8 v) {
    v = __builtin_elementwise_min(v, splat8(1.0f));
    v = __builtin_elementwise_max(v, splat8(-1.0f));
    return v;
}

// All 20 iterations fused, TILE=80 (halo redundancy 2.25x), 16-wave blocks
// x 2 blocks/CU = 32 waves/CU (exactly 8/EU -> launch_bounds consistent).
// LDS: xt plane, yv plane, yh-edge array (61.2 KB). Thread state
// (sigma*w, CF*img, x, yh, yv) in fp16 regs, all math packed fp16.
// BCs data-encoded (w=0 outside image / last col / last row); halo
// invalidates 1/side/iter, HALO=20 covers 20 iters; out-of-range halo
// reads land on finite always-written LDS and feed only cone-invalid
// pixels (validated rounds 4-8).
__global__ __launch_bounds__(NT, 8) void fused_pd(
    const float* __restrict__ img,
    const float* __restrict__ wg,    // (2,H,W): wg[0]=w_h, wg[N]=w_v
    float* __restrict__ out)
{
    __shared__ _Float16 lds_s[2 * PS + NCH + 2];   // 61,204 B -> 2 blocks/CU
    _Float16* __restrict__ xtp = lds_s;            // x_tilde plane
    _Float16* __restrict__ yvp = lds_s + PS;       // y vertical plane
    _Float16* __restrict__ yhe = lds_s + 2 * PS;   // yh edges: yhe[t+1] = yh[7] of chunk t

    const int tid = threadIdx.x;
    const int gi0 = blockIdx.y * TILE - HALO;
    const int gj0 = blockIdx.x * TILE - HALO;
    const bool interior = (gi0 >= 0) && (gj0 >= 0) && (gi0 + R <= H) && (gj0 + R <= W);

    const int t0 = tid, t1 = tid + NT;
    const int i0_ = t0 / CPR, i1_ = t1 / CPR;
    const int b0 = i0_ * S + (t0 - i0_ * CPR) * 8;
    const int b1 = i1_ * S + (t1 - i1_ * CPR) * 8;
    const bool act1 = (t1 < NCH);

    // packed loop constants
    const half8 kTIV  = splat8(TIV);
    const half8 kINVD = splat8(INVD);
    const half8 k15   = splat8(1.5f);
    const half8 kM05  = splat8(-0.5f);

    // persistent per-chunk register state (fp16)
    half8 wh0, wh1, wv0, wv1;   // SIGMA*w
    half8 ci0, ci1;             // CF*img
    half8 x0, x1;               // x
    half8 yh0, yh1, yv0, yv1;   // dual state

    // ---------------- load & init ----------------
    auto loadC = [&](int t, half8& whr, half8& wvr, half8& cir, half8& xr) {
        const int i  = t / CPR;
        const int j0 = (t - i * CPR) * 8;
        const int gi = gi0 + i;
        const int gj = gj0 + j0;
        float im[8], wh[8], wv[8];
        if (interior) {
            const float4* ip = reinterpret_cast<const float4*>(img + (long)gi * W + gj);
            float4 a = ip[0], b = ip[1];
            im[0]=a.x; im[1]=a.y; im[2]=a.z; im[3]=a.w;
            im[4]=b.x; im[5]=b.y; im[6]=b.z; im[7]=b.w;
            const float4* hp = reinterpret_cast<const float4*>(wg + (long)gi * W + gj);
            float4 c = hp[0], d = hp[1];
            wh[0]=c.x*SIGMA; wh[1]=c.y*SIGMA; wh[2]=c.z*SIGMA; wh[3]=c.w*SIGMA;
            wh[4]=d.x*SIGMA; wh[5]=d.y*SIGMA; wh[6]=d.z*SIGMA; wh[7]=d.w*SIGMA;
            const float4* vp = reinterpret_cast<const float4*>(wg + N + (long)gi * W + gj);
            float4 e = vp[0], f = vp[1];
            wv[0]=e.x*SIGMA; wv[1]=e.y*SIGMA; wv[2]=e.z*SIGMA; wv[3]=e.w*SIGMA;
            wv[4]=f.x*SIGMA; wv[5]=f.y*SIGMA; wv[6]=f.z*SIGMA; wv[7]=f.w*SIGMA;
        } else {
            const int gic = min(max(gi, 0), H - 1);
            const bool rowin = (gi >= 0) && (gi < H);
#pragma unroll
            for (int k = 0; k < 8; ++k) {
                const int gjk = gj + k;
                const int gjc = min(max(gjk, 0), W - 1);
                const bool inim = rowin && (gjk >= 0) && (gjk < W);
                const long o = (long)gic * W + gjc;
                im[k] = img[o];
                wh[k] = (inim && gjk < W - 1) ? SIGMA * wg[o]     : 0.0f;
                wv[k] = (inim && gi  < H - 1) ? SIGMA * wg[N + o] : 0.0f;
            }
        }
        half8 imv;
#pragma unroll
        for (int k = 0; k < 8; ++k) {
            imv[k] = (_Float16)im[k];
            whr[k] = (_Float16)wh[k];
            wvr[k] = (_Float16)wv[k];
            cir[k] = (_Float16)(CF * im[k]);
        }
        xr = imv;
        *reinterpret_cast<half8*>(xtp + i * S + j0) = imv;   // xt = img
    };
    loadC(t0, wh0, wv0, ci0, x0);
    if (act1) loadC(t1, wh1, wv1, ci1, x1);
    yh0 = splat8(0.f); yh1 = splat8(0.f);
    yv0 = splat8(0.f); yv1 = splat8(0.f);
    if (tid == 0) yhe[0] = (_Float16)0.0f;   // left edge of chunk 0
    __syncthreads();

    for (int it = 0; it < 20; ++it) {
        // -------- dual: y = clamp(y + grad(xt) * (SIGMA*w)), packed fp16 --------
        auto dualC = [&](int t, int base, half8 wh, half8 wv, half8& yh, half8& yv) {
            half8 cv = *reinterpret_cast<const half8*>(xtp + base);
            _Float16 rt = xtp[base + 8];
            half8 bv = *reinterpret_cast<const half8*>(xtp + base + S);
            half8 sh = __builtin_shufflevector(cv, cv, 1, 2, 3, 4, 5, 6, 7, 7);
            sh[7] = rt;
            yh = clamp8((sh - cv) * wh + yh);   // pk_fma
            yv = clamp8((bv - cv) * wv + yv);   // pk_fma
            *reinterpret_cast<half8*>(yvp + base) = yv;
            yhe[t + 1] = yh[7];
        };
        dualC(t0, b0, wh0, wv0, yh0, yv0);
        if (act1) dualC(t1, b1, wh1, wv1, yh1, yv1);
        __syncthreads();

        // -------- primal, packed fp16:
        //   xn = x*INVD + (TIV*dv + ci);  xt = 1.5*xn - 0.5*x --------
        auto primC = [&](int t, int base, half8 yh, half8 yv, half8 ci, half8& x) {
            _Float16 yl = yhe[t];
            half8 yva = *reinterpret_cast<const half8*>(yvp + base - S);
            half8 ysh = __builtin_shufflevector(yh, yh, 0, 0, 1, 2, 3, 4, 5, 6);
            ysh[0] = yl;
            half8 dv = (yh - ysh) + (yv - yva);
            half8 tt = dv * kTIV + ci;          // pk_fma
            half8 xn = x * kINVD + tt;          // pk_fma
            half8 xt = xn * k15 + x * kM05;     // pk_mul + pk_fma
            x = xn;
            *reinterpret_cast<half8*>(xtp + base) = xt;
        };
        primC(t0, b0, yh0, yv0, ci0, x0);
        if (act1) primC(t1, b1, yh1, yv1, ci1, x1);
        __syncthreads();
    }

    // ---------------- store center 80x80 as fp32 (guarded) ----------------
    if (tid < TILE * (TILE / 8)) {           // 800 store tasks, 8 px each
        const int r = tid / (TILE / 8);      // 0..79
        const int c = tid - r * (TILE / 8);  // 0..9
        const int gr = blockIdx.y * TILE + r;
        const int gc = blockIdx.x * TILE + c * 8;
        if (gr < H && gc < W) {
            const int base = (HALO + r) * S + HALO + c * 8;   // 8B-aligned
            half4v a = *reinterpret_cast<const half4v*>(xtp + base);
            half4v b = *reinterpret_cast<const half4v*>(xtp + base + 4);
            float4 o0 = make_float4((float)a[0], (float)a[1], (float)a[2], (float)a[3]);
            float4 o1 = make_float4((float)b[0], (float)b[1], (float)b[2], (float)b[3]);
            const long g = (long)gr * W + gc;
            *reinterpret_cast<float4*>(out + g)     = o0;
            *reinterpret_cast<float4*>(out + g + 4) = o1;
        }
    }
}

extern "C" void kernel_launch(void* const* d_in, const int* in_sizes, int n_in,
                              void* d_out, int out_size, void* d_ws, size_t ws_size,
                              hipStream_t stream) {
    const float* img = (const float*)d_in[0];   // (1,H,W)
    const float* wg  = (const float*)d_in[1];   // (2,H,W)
    float* out = (float*)d_out;

    dim3 grid(GRID, GRID);                      // 52 x 52 = 2704 blocks
    fused_pd<<<grid, dim3(NT), 0, stream>>>(img, wg, out);
}

// Round 11
// 541.407 us; speedup vs baseline: 3.1239x; 3.0213x over previous
//
#include <hip/hip_runtime.h>

static constexpr int H = 4096;
static constexpr int W = 4096;
static constexpr long N = (long)H * W;

static constexpr int TILE = 80;
static constexpr int HALO = 20;              // one per iteration per side
static constexpr int R    = TILE + 2*HALO;   // 120 region
static constexpr int S    = R;               // row stride (halfs)
static constexpr int PS   = R * S;           // plane size (halfs) = 14400
static constexpr int CPR  = R / 8;           // 15 chunks per row
static constexpr int NCH  = R * CPR;         // 1800 half8-chunk tasks
static constexpr int NT   = 1024;            // 16 waves; 2 blocks/CU (LDS-limited)
static constexpr int GRID = 52;              // ceil(4096/80)

static constexpr float SIGMA = 14.285714285714286f;  // 1/(7*0.01)
static constexpr float INVD  = 1.0f / 1.07f;
static constexpr float TIV   = 0.01f / 1.07f;        // TAU/(1+LT)
static constexpr float CF    = 0.07f / 1.07f;        // LAMBDA*TAU/(1+LT)

typedef _Float16 half8  __attribute__((ext_vector_type(8)));
typedef _Float16 half4v __attribute__((ext_vector_type(4)));

__device__ __forceinline__ half8 splat8(float f) {
    _Float16 h = (_Float16)f;
    half8 v = {h, h, h, h, h, h, h, h};
    return v;
}
__device__ __forceinline__ half8 clamp8(half8 v) {
    v = __builtin_elementwise_min(v, splat8(1.0f));
    v = __builtin_elementwise_max(v, splat8(-1.0f));
    return v;
}

// All 20 iterations fused, TILE=80 (halo redundancy 2.25x), 16-wave blocks,
// 2 blocks/CU (LDS-limited) = 32 waves/CU. launch_bounds(1024, 2): under
// either arg-semantics this caps VGPR at >=64; kernel needs ~40 -> no spill
// (rounds 9/10 failed purely on a degenerate 32-VGPR cap from arg=8).
// LDS: xt plane, yv plane, yh-edge array (61.2 KB). Thread state
// (sigma*w, CF*img, x, yh, yv) in fp16 regs, all math packed fp16.
// BCs data-encoded (w=0 outside image / last col / last row); halo
// invalidates 1/side/iter, HALO=20 covers 20 iters; out-of-range halo
// reads land on finite always-written LDS and feed only cone-invalid
// pixels (validated rounds 4-8).
__global__ __launch_bounds__(NT, 2) void fused_pd(
    const float* __restrict__ img,
    const float* __restrict__ wg,    // (2,H,W): wg[0]=w_h, wg[N]=w_v
    float* __restrict__ out)
{
    __shared__ _Float16 lds_s[2 * PS + NCH + 2];   // 61,204 B -> 2 blocks/CU
    _Float16* __restrict__ xtp = lds_s;            // x_tilde plane
    _Float16* __restrict__ yvp = lds_s + PS;       // y vertical plane
    _Float16* __restrict__ yhe = lds_s + 2 * PS;   // yh edges: yhe[t+1] = yh[7] of chunk t

    const int tid = threadIdx.x;
    const int gi0 = blockIdx.y * TILE - HALO;
    const int gj0 = blockIdx.x * TILE - HALO;
    const bool interior = (gi0 >= 0) && (gj0 >= 0) && (gi0 + R <= H) && (gj0 + R <= W);

    const int t0 = tid, t1 = tid + NT;
    const int i0_ = t0 / CPR, i1_ = t1 / CPR;
    const int b0 = i0_ * S + (t0 - i0_ * CPR) * 8;
    const int b1 = i1_ * S + (t1 - i1_ * CPR) * 8;
    const bool act1 = (t1 < NCH);

    // packed loop constants
    const half8 kTIV  = splat8(TIV);
    const half8 kINVD = splat8(INVD);
    const half8 k15   = splat8(1.5f);
    const half8 kM05  = splat8(-0.5f);

    // persistent per-chunk register state (fp16)
    half8 wh0, wh1, wv0, wv1;   // SIGMA*w
    half8 ci0, ci1;             // CF*img
    half8 x0, x1;               // x
    half8 yh0, yh1, yv0, yv1;   // dual state

    // ---------------- load & init ----------------
    auto loadC = [&](int t, half8& whr, half8& wvr, half8& cir, half8& xr) {
        const int i  = t / CPR;
        const int j0 = (t - i * CPR) * 8;
        const int gi = gi0 + i;
        const int gj = gj0 + j0;
        float im[8], wh[8], wv[8];
        if (interior) {
            const float4* ip = reinterpret_cast<const float4*>(img + (long)gi * W + gj);
            float4 a = ip[0], b = ip[1];
            im[0]=a.x; im[1]=a.y; im[2]=a.z; im[3]=a.w;
            im[4]=b.x; im[5]=b.y; im[6]=b.z; im[7]=b.w;
            const float4* hp = reinterpret_cast<const float4*>(wg + (long)gi * W + gj);
            float4 c = hp[0], d = hp[1];
            wh[0]=c.x*SIGMA; wh[1]=c.y*SIGMA; wh[2]=c.z*SIGMA; wh[3]=c.w*SIGMA;
            wh[4]=d.x*SIGMA; wh[5]=d.y*SIGMA; wh[6]=d.z*SIGMA; wh[7]=d.w*SIGMA;
            const float4* vp = reinterpret_cast<const float4*>(wg + N + (long)gi * W + gj);
            float4 e = vp[0], f = vp[1];
            wv[0]=e.x*SIGMA; wv[1]=e.y*SIGMA; wv[2]=e.z*SIGMA; wv[3]=e.w*SIGMA;
            wv[4]=f.x*SIGMA; wv[5]=f.y*SIGMA; wv[6]=f.z*SIGMA; wv[7]=f.w*SIGMA;
        } else {
            const int gic = min(max(gi, 0), H - 1);
            const bool rowin = (gi >= 0) && (gi < H);
#pragma unroll
            for (int k = 0; k < 8; ++k) {
                const int gjk = gj + k;
                const int gjc = min(max(gjk, 0), W - 1);
                const bool inim = rowin && (gjk >= 0) && (gjk < W);
                const long o = (long)gic * W + gjc;
                im[k] = img[o];
                wh[k] = (inim && gjk < W - 1) ? SIGMA * wg[o]     : 0.0f;
                wv[k] = (inim && gi  < H - 1) ? SIGMA * wg[N + o] : 0.0f;
            }
        }
        half8 imv;
#pragma unroll
        for (int k = 0; k < 8; ++k) {
            imv[k] = (_Float16)im[k];
            whr[k] = (_Float16)wh[k];
            wvr[k] = (_Float16)wv[k];
            cir[k] = (_Float16)(CF * im[k]);
        }
        xr = imv;
        *reinterpret_cast<half8*>(xtp + i * S + j0) = imv;   // xt = img
    };
    loadC(t0, wh0, wv0, ci0, x0);
    if (act1) loadC(t1, wh1, wv1, ci1, x1);
    yh0 = splat8(0.f); yh1 = splat8(0.f);
    yv0 = splat8(0.f); yv1 = splat8(0.f);
    if (tid == 0) yhe[0] = (_Float16)0.0f;   // left edge of chunk 0
    __syncthreads();

    for (int it = 0; it < 20; ++it) {
        // -------- dual: y = clamp(y + grad(xt) * (SIGMA*w)), packed fp16 --------
        auto dualC = [&](int t, int base, half8 wh, half8 wv, half8& yh, half8& yv) {
            half8 cv = *reinterpret_cast<const half8*>(xtp + base);
            _Float16 rt = xtp[base + 8];
            half8 bv = *reinterpret_cast<const half8*>(xtp + base + S);
            half8 sh = __builtin_shufflevector(cv, cv, 1, 2, 3, 4, 5, 6, 7, 7);
            sh[7] = rt;
            yh = clamp8((sh - cv) * wh + yh);   // pk_fma
            yv = clamp8((bv - cv) * wv + yv);   // pk_fma
            *reinterpret_cast<half8*>(yvp + base) = yv;
            yhe[t + 1] = yh[7];
        };
        dualC(t0, b0, wh0, wv0, yh0, yv0);
        if (act1) dualC(t1, b1, wh1, wv1, yh1, yv1);
        __syncthreads();

        // -------- primal, packed fp16:
        //   xn = x*INVD + (TIV*dv + ci);  xt = 1.5*xn - 0.5*x --------
        auto primC = [&](int t, int base, half8 yh, half8 yv, half8 ci, half8& x) {
            _Float16 yl = yhe[t];
            half8 yva = *reinterpret_cast<const half8*>(yvp + base - S);
            half8 ysh = __builtin_shufflevector(yh, yh, 0, 0, 1, 2, 3, 4, 5, 6);
            ysh[0] = yl;
            half8 dv = (yh - ysh) + (yv - yva);
            half8 tt = dv * kTIV + ci;          // pk_fma
            half8 xn = x * kINVD + tt;          // pk_fma
            half8 xt = xn * k15 + x * kM05;     // pk_mul + pk_fma
            x = xn;
            *reinterpret_cast<half8*>(xtp + base) = xt;
        };
        primC(t0, b0, yh0, yv0, ci0, x0);
        if (act1) primC(t1, b1, yh1, yv1, ci1, x1);
        __syncthreads();
    }

    // ---------------- store center 80x80 as fp32 (guarded) ----------------
    if (tid < TILE * (TILE / 8)) {           // 800 store tasks, 8 px each
        const int r = tid / (TILE / 8);      // 0..79
        const int c = tid - r * (TILE / 8);  // 0..9
        const int gr = blockIdx.y * TILE + r;
        const int gc = blockIdx.x * TILE + c * 8;
        if (gr < H && gc < W) {
            const int base = (HALO + r) * S + HALO + c * 8;   // 8B-aligned
            half4v a = *reinterpret_cast<const half4v*>(xtp + base);
            half4v b = *reinterpret_cast<const half4v*>(xtp + base + 4);
            float4 o0 = make_float4((float)a[0], (float)a[1], (float)a[2], (float)a[3]);
            float4 o1 = make_float4((float)b[0], (float)b[1], (float)b[2], (float)b[3]);
            const long g = (long)gr * W + gc;
            *reinterpret_cast<float4*>(out + g)     = o0;
            *reinterpret_cast<float4*>(out + g + 4) = o1;
        }
    }
}

extern "C" void kernel_launch(void* const* d_in, const int* in_sizes, int n_in,
                              void* d_out, int out_size, void* d_ws, size_t ws_size,
                              hipStream_t stream) {
    const float* img = (const float*)d_in[0];   // (1,H,W)
    const float* wg  = (const float*)d_in[1];   // (2,H,W)
    float* out = (float*)d_out;

    dim3 grid(GRID, GRID);                      // 52 x 52 = 2704 blocks
    fused_pd<<<grid, dim3(NT), 0, stream>>>(img, wg, out);
}

// Round 12
// 423.449 us; speedup vs baseline: 3.9941x; 1.2786x over previous
//
#include <hip/hip_runtime.h>

static constexpr int H = 4096;
static constexpr int W = 4096;
static constexpr long N = (long)H * W;

static constexpr int TILE = 64;
static constexpr int HOFF = 12;              // halo capacity; 10 needed per phase
static constexpr int R    = TILE + 2*HOFF;   // 88
static constexpr int S    = R;               // row stride (halfs)
static constexpr int PS   = R * S;           // 7744 halfs
static constexpr int CPR  = R / 8;           // 11 chunks per row
static constexpr int NCH  = R * CPR;         // 968 chunk tasks
static constexpr int NT   = 512;             // 8 waves; 4 blocks/CU = 32 waves/CU

static constexpr float SIGMA = 14.285714285714286f;  // 1/(7*0.01)
static constexpr float INVD  = 1.0f / 1.07f;
static constexpr float TIV   = 0.01f / 1.07f;        // TAU/(1+LT)
static constexpr float CF    = 0.07f / 1.07f;        // LAMBDA*TAU/(1+LT)

typedef _Float16 half8  __attribute__((ext_vector_type(8)));
typedef _Float16 half4v __attribute__((ext_vector_type(4)));

__device__ __forceinline__ half8 splat8(float f) {
    _Float16 h = (_Float16)f;
    half8 v = {h, h, h, h, h, h, h, h};
    return v;
}
__device__ __forceinline__ half8 clamp8(half8 v) {
    v = __builtin_elementwise_min(v, splat8(1.0f));
    v = __builtin_elementwise_max(v, splat8(-1.0f));
    return v;
}

// ---------------- pack: whp = SIGMA*w_h (0 at col W-1), wvp = SIGMA*w_v (0 at row H-1)
__global__ __launch_bounds__(256) void pack_w(
    const float* __restrict__ wg, _Float16* __restrict__ whp, _Float16* __restrict__ wvp)
{
    const long p = ((long)blockIdx.x * 256 + threadIdx.x) * 8;
    const int i = (int)(p >> 12);
    const float4* hp = reinterpret_cast<const float4*>(wg + p);
    float4 a = hp[0], b = hp[1];
    const float4* vp = reinterpret_cast<const float4*>(wg + N + p);
    float4 c = vp[0], d = vp[1];
    half8 wh, wv;
    wh[0]=(_Float16)(SIGMA*a.x); wh[1]=(_Float16)(SIGMA*a.y);
    wh[2]=(_Float16)(SIGMA*a.z); wh[3]=(_Float16)(SIGMA*a.w);
    wh[4]=(_Float16)(SIGMA*b.x); wh[5]=(_Float16)(SIGMA*b.y);
    wh[6]=(_Float16)(SIGMA*b.z); wh[7]=(_Float16)(SIGMA*b.w);
    wv[0]=(_Float16)(SIGMA*c.x); wv[1]=(_Float16)(SIGMA*c.y);
    wv[2]=(_Float16)(SIGMA*c.z); wv[3]=(_Float16)(SIGMA*c.w);
    wv[4]=(_Float16)(SIGMA*d.x); wv[5]=(_Float16)(SIGMA*d.y);
    wv[6]=(_Float16)(SIGMA*d.z); wv[7]=(_Float16)(SIGMA*d.w);
    if ((p & 4095) + 8 == W) wh[7] = (_Float16)0.0f;   // gh BC at last col
    if (i == H - 1) wv = splat8(0.0f);                 // gv BC at last row
    *reinterpret_cast<half8*>(whp + p) = wh;
    *reinterpret_cast<half8*>(wvp + p) = wv;
}

// ---------------- phase kernel: 10 iterations, round-8 structure ----------------
// PHASE 0: x=xt=img, y=0; stores center {x, xt, yh, yv} fp16 planes.
// PHASE 1: loads state planes; stores center xt as fp32 to out.
// LDS: xt plane + yv plane + yh-edge array. BCs data-encoded (w=0). Halo
// invalidates 1 ring/iter; 10 iters <= HOFF-2. Out-of-range halo reads land
// on finite LDS and feed only cone-invalid pixels (validated rounds 4-8).
template<int PHASE>
__global__ __launch_bounds__(NT, 4) void fused_pd(
    const float* __restrict__ img,
    const _Float16* __restrict__ whp, const _Float16* __restrict__ wvp,
    _Float16* __restrict__ xg,  _Float16* __restrict__ xtg,
    _Float16* __restrict__ yhg, _Float16* __restrict__ yvg,
    float* __restrict__ out)
{
    __shared__ _Float16 lds_s[2 * PS + NCH + 2];   // 17,410 halfs = 34,820 B
    _Float16* __restrict__ xtp = lds_s;
    _Float16* __restrict__ yvp = lds_s + PS;
    _Float16* __restrict__ yhe = lds_s + 2 * PS;

    const int tid = threadIdx.x;
    const int gi0 = blockIdx.y * TILE - HOFF;
    const int gj0 = blockIdx.x * TILE - HOFF;
    const bool interior = (gi0 >= 0) && (gj0 >= 0) && (gi0 + R <= H) && (gj0 + R <= W);

    const int t0 = tid, t1 = tid + NT;
    const int i0_ = t0 / CPR, i1_ = t1 / CPR;
    const int b0 = i0_ * S + (t0 - i0_ * CPR) * 8;
    const int b1 = i1_ * S + (t1 - i1_ * CPR) * 8;
    const bool act1 = (t1 < NCH);

    const half8 kTIV  = splat8(TIV);
    const half8 kINVD = splat8(INVD);
    const half8 k15   = splat8(1.5f);
    const half8 kM05  = splat8(-0.5f);

    half8 wh0, wh1, wv0, wv1;   // SIGMA*w (BC-baked)
    half8 ci0, ci1;             // CF*img
    half8 x0, x1;               // primal state
    half8 yh0, yh1, yv0, yv1;   // dual state

    auto loadC = [&](int t, half8& whr, half8& wvr, half8& cir, half8& xr,
                     half8& yhr, half8& yvr) {
        const int i  = t / CPR;
        const int j0 = (t - i * CPR) * 8;
        const int gi = gi0 + i;
        const int gj = gj0 + j0;
        half8 xtv;
        if (interior) {
            const long o = (long)gi * W + gj;
            const float4* ip = reinterpret_cast<const float4*>(img + o);
            float4 a = ip[0], b = ip[1];
            float im[8] = {a.x, a.y, a.z, a.w, b.x, b.y, b.z, b.w};
            whr = *reinterpret_cast<const half8*>(whp + o);
            wvr = *reinterpret_cast<const half8*>(wvp + o);
#pragma unroll
            for (int k = 0; k < 8; ++k) cir[k] = (_Float16)(CF * im[k]);
            if (PHASE == 0) {
#pragma unroll
                for (int k = 0; k < 8; ++k) xr[k] = (_Float16)im[k];
                xtv = xr;
                yhr = splat8(0.f); yvr = splat8(0.f);
            } else {
                xr  = *reinterpret_cast<const half8*>(xg  + o);
                xtv = *reinterpret_cast<const half8*>(xtg + o);
                yhr = *reinterpret_cast<const half8*>(yhg + o);
                yvr = *reinterpret_cast<const half8*>(yvg + o);
            }
        } else {
            const int gic = min(max(gi, 0), H - 1);
            const bool rowin = (gi >= 0) && (gi < H);
#pragma unroll
            for (int k = 0; k < 8; ++k) {
                const int gjk = gj + k;
                const int gjc = min(max(gjk, 0), W - 1);
                const bool inim = rowin && (gjk >= 0) && (gjk < W);
                const long o = (long)gic * W + gjc;
                const float imf = img[o];
                whr[k] = inim ? whp[o] : (_Float16)0.0f;
                wvr[k] = inim ? wvp[o] : (_Float16)0.0f;
                cir[k] = (_Float16)(CF * imf);
                if (PHASE == 0) {
                    xr[k]  = (_Float16)imf;
                    xtv[k] = (_Float16)imf;
                    yhr[k] = (_Float16)0.0f;
                    yvr[k] = (_Float16)0.0f;
                } else {
                    xr[k]  = xg[o];
                    xtv[k] = xtg[o];
                    yhr[k] = inim ? yhg[o] : (_Float16)0.0f;
                    yvr[k] = inim ? yvg[o] : (_Float16)0.0f;
                }
            }
        }
        *reinterpret_cast<half8*>(xtp + i * S + j0) = xtv;
    };
    loadC(t0, wh0, wv0, ci0, x0, yh0, yv0);
    if (act1) loadC(t1, wh1, wv1, ci1, x1, yh1, yv1);
    if (tid == 0) yhe[0] = (_Float16)0.0f;
    __syncthreads();

    for (int it = 0; it < 10; ++it) {
        auto dualC = [&](int t, int base, half8 wh, half8 wv, half8& yh, half8& yv) {
            half8 cv = *reinterpret_cast<const half8*>(xtp + base);
            _Float16 rt = xtp[base + 8];
            half8 bv = *reinterpret_cast<const half8*>(xtp + base + S);
            half8 sh = __builtin_shufflevector(cv, cv, 1, 2, 3, 4, 5, 6, 7, 7);
            sh[7] = rt;
            yh = clamp8((sh - cv) * wh + yh);
            yv = clamp8((bv - cv) * wv + yv);
            *reinterpret_cast<half8*>(yvp + base) = yv;
            yhe[t + 1] = yh[7];
        };
        dualC(t0, b0, wh0, wv0, yh0, yv0);
        if (act1) dualC(t1, b1, wh1, wv1, yh1, yv1);
        __syncthreads();

        auto primC = [&](int t, int base, half8 yh, half8 yv, half8 ci, half8& x) {
            _Float16 yl = yhe[t];
            half8 yva = *reinterpret_cast<const half8*>(yvp + base - S);
            half8 ysh = __builtin_shufflevector(yh, yh, 0, 0, 1, 2, 3, 4, 5, 6);
            ysh[0] = yl;
            half8 dv = (yh - ysh) + (yv - yva);
            half8 tt = dv * kTIV + ci;
            half8 xn = x * kINVD + tt;
            half8 xt = xn * k15 + x * kM05;
            x = xn;
            *reinterpret_cast<half8*>(xtp + base) = xt;
        };
        primC(t0, b0, yh0, yv0, ci0, x0);
        if (act1) primC(t1, b1, yh1, yv1, ci1, x1);
        __syncthreads();
    }

    // ---------------- stores ----------------
    const int r  = tid >> 3;           // 0..63
    const int k  = tid & 7;            // 0..7
    const int lb = (HOFF + r) * S + HOFF + k * 8;          // 8B-aligned (two half4)
    const long gb = (long)(blockIdx.y * TILE + r) * W + blockIdx.x * TILE + k * 8;

    if (PHASE == 0) {
        // pass 1: xt (xtp) -> xtg, yv (yvp) -> yvg
        {
            half4v a0 = *reinterpret_cast<const half4v*>(xtp + lb);
            half4v a1 = *reinterpret_cast<const half4v*>(xtp + lb + 4);
            half8 o; o[0]=a0[0];o[1]=a0[1];o[2]=a0[2];o[3]=a0[3];
                     o[4]=a1[0];o[5]=a1[1];o[6]=a1[2];o[7]=a1[3];
            *reinterpret_cast<half8*>(xtg + gb) = o;
            half4v b0v = *reinterpret_cast<const half4v*>(yvp + lb);
            half4v b1v = *reinterpret_cast<const half4v*>(yvp + lb + 4);
            half8 o2; o2[0]=b0v[0];o2[1]=b0v[1];o2[2]=b0v[2];o2[3]=b0v[3];
                      o2[4]=b1v[0];o2[5]=b1v[1];o2[6]=b1v[2];o2[7]=b1v[3];
            *reinterpret_cast<half8*>(yvg + gb) = o2;
        }
        __syncthreads();
        // bounce: x -> xtp, yh -> yvp
        *reinterpret_cast<half8*>(xtp + b0) = x0;
        *reinterpret_cast<half8*>(yvp + b0) = yh0;
        if (act1) {
            *reinterpret_cast<half8*>(xtp + b1) = x1;
            *reinterpret_cast<half8*>(yvp + b1) = yh1;
        }
        __syncthreads();
        // pass 2: x -> xg, yh -> yhg
        {
            half4v a0 = *reinterpret_cast<const half4v*>(xtp + lb);
            half4v a1 = *reinterpret_cast<const half4v*>(xtp + lb + 4);
            half8 o; o[0]=a0[0];o[1]=a0[1];o[2]=a0[2];o[3]=a0[3];
                     o[4]=a1[0];o[5]=a1[1];o[6]=a1[2];o[7]=a1[3];
            *reinterpret_cast<half8*>(xg + gb) = o;
            half4v b0v = *reinterpret_cast<const half4v*>(yvp + lb);
            half4v b1v = *reinterpret_cast<const half4v*>(yvp + lb + 4);
            half8 o2; o2[0]=b0v[0];o2[1]=b0v[1];o2[2]=b0v[2];o2[3]=b0v[3];
                      o2[4]=b1v[0];o2[5]=b1v[1];o2[6]=b1v[2];o2[7]=b1v[3];
            *reinterpret_cast<half8*>(yhg + gb) = o2;
        }
    } else {
        half4v a = *reinterpret_cast<const half4v*>(xtp + lb);
        half4v b = *reinterpret_cast<const half4v*>(xtp + lb + 4);
        float4 o0 = make_float4((float)a[0], (float)a[1], (float)a[2], (float)a[3]);
        float4 o1 = make_float4((float)b[0], (float)b[1], (float)b[2], (float)b[3]);
        *reinterpret_cast<float4*>(out + gb)     = o0;
        *reinterpret_cast<float4*>(out + gb + 4) = o1;
    }
}

extern "C" void kernel_launch(void* const* d_in, const int* in_sizes, int n_in,
                              void* d_out, int out_size, void* d_ws, size_t ws_size,
                              hipStream_t stream) {
    const float* img = (const float*)d_in[0];   // (1,H,W)
    const float* wg  = (const float*)d_in[1];   // (2,H,W)
    float* out = (float*)d_out;

    _Float16* ws16 = (_Float16*)d_ws;           // 6 fp16 planes = 12N bytes
    _Float16* whp = ws16;
    _Float16* wvp = ws16 + N;
    _Float16* xg  = ws16 + 2 * N;
    _Float16* xtg = ws16 + 3 * N;
    _Float16* yhg = ws16 + 4 * N;
    _Float16* yvg = ws16 + 5 * N;

    pack_w<<<dim3((int)(N / 8 / 256)), dim3(256), 0, stream>>>(wg, whp, wvp);

    dim3 grid(W / TILE, H / TILE);              // 64 x 64 = 4096 blocks
    fused_pd<0><<<grid, dim3(NT), 0, stream>>>(img, whp, wvp, xg, xtg, yhg, yvg, out);
    fused_pd<1><<<grid, dim3(NT), 0, stream>>>(img, whp, wvp, xg, xtg, yhg, yvg, out);
}

// Round 13
// 369.367 us; speedup vs baseline: 4.5789x; 1.1464x over previous
//
#include <hip/hip_runtime.h>

static constexpr int H = 4096;
static constexpr int W = 4096;
static constexpr long N = (long)H * W;

static constexpr int TILE = 64;
static constexpr int HOFF = 12;              // halo capacity; 10 needed per phase
static constexpr int R    = TILE + 2*HOFF;   // 88
static constexpr int S    = R;               // row stride (halfs)
static constexpr int PS   = R * S;           // 7744 halfs
static constexpr int CPR  = R / 8;           // 11 chunks per row
static constexpr int NCH  = R * CPR;         // 968 chunk tasks
static constexpr int NT   = 512;             // 8 waves; 4 blocks/CU = 32 waves/CU

static constexpr float SIGMA = 14.285714285714286f;  // 1/(7*0.01)
static constexpr float INVD  = 1.0f / 1.07f;
static constexpr float TIV   = 0.01f / 1.07f;        // TAU/(1+LT)
static constexpr float CF    = 0.07f / 1.07f;        // LAMBDA*TAU/(1+LT)

typedef _Float16 half8  __attribute__((ext_vector_type(8)));
typedef _Float16 half4v __attribute__((ext_vector_type(4)));

__device__ __forceinline__ half8 splat8(float f) {
    _Float16 h = (_Float16)f;
    half8 v = {h, h, h, h, h, h, h, h};
    return v;
}
__device__ __forceinline__ half8 clamp8(half8 v) {
    v = __builtin_elementwise_min(v, splat8(1.0f));
    v = __builtin_elementwise_max(v, splat8(-1.0f));
    return v;
}

// ---------------- pack: whp = SIGMA*w_h (0 at col W-1), wvp = SIGMA*w_v (0 at row H-1)
__global__ __launch_bounds__(256) void pack_w(
    const float* __restrict__ wg, _Float16* __restrict__ whp, _Float16* __restrict__ wvp)
{
    const long p = ((long)blockIdx.x * 256 + threadIdx.x) * 8;
    const int i = (int)(p >> 12);
    const float4* hp = reinterpret_cast<const float4*>(wg + p);
    float4 a = hp[0], b = hp[1];
    const float4* vp = reinterpret_cast<const float4*>(wg + N + p);
    float4 c = vp[0], d = vp[1];
    half8 wh, wv;
    wh[0]=(_Float16)(SIGMA*a.x); wh[1]=(_Float16)(SIGMA*a.y);
    wh[2]=(_Float16)(SIGMA*a.z); wh[3]=(_Float16)(SIGMA*a.w);
    wh[4]=(_Float16)(SIGMA*b.x); wh[5]=(_Float16)(SIGMA*b.y);
    wh[6]=(_Float16)(SIGMA*b.z); wh[7]=(_Float16)(SIGMA*b.w);
    wv[0]=(_Float16)(SIGMA*c.x); wv[1]=(_Float16)(SIGMA*c.y);
    wv[2]=(_Float16)(SIGMA*c.z); wv[3]=(_Float16)(SIGMA*c.w);
    wv[4]=(_Float16)(SIGMA*d.x); wv[5]=(_Float16)(SIGMA*d.y);
    wv[6]=(_Float16)(SIGMA*d.z); wv[7]=(_Float16)(SIGMA*d.w);
    if ((p & 4095) + 8 == W) wh[7] = (_Float16)0.0f;   // gh BC at last col
    if (i == H - 1) wv = splat8(0.0f);                 // gv BC at last row
    *reinterpret_cast<half8*>(whp + p) = wh;
    *reinterpret_cast<half8*>(wvp + p) = wv;
}

// ---------------- phase kernel: 10 iterations ----------------
// PHASE 0: x=xt=img, y=0; stores center {x, xt, yh, yv} fp16 planes.
// PHASE 1: loads state planes; stores center xt as fp32 to out.
// Own-chunk xt kept in a persistent register (saves 1 ds_read_b128/chunk-iter);
// LDS copy written only for neighbors' rt/bv reads. LDS: xt plane + yv plane +
// yh-edge array. BCs data-encoded (w=0). Halo invalidates 1 ring/iter;
// 10 iters <= HOFF-2. Out-of-range halo reads land on finite LDS and feed only
// cone-invalid pixels (validated rounds 4-12).
template<int PHASE>
__global__ __launch_bounds__(NT, 4) void fused_pd(
    const float* __restrict__ img,
    const _Float16* __restrict__ whp, const _Float16* __restrict__ wvp,
    _Float16* __restrict__ xg,  _Float16* __restrict__ xtg,
    _Float16* __restrict__ yhg, _Float16* __restrict__ yvg,
    float* __restrict__ out)
{
    __shared__ _Float16 lds_s[2 * PS + NCH + 2];   // 17,410 halfs = 34,820 B
    _Float16* __restrict__ xtp = lds_s;
    _Float16* __restrict__ yvp = lds_s + PS;
    _Float16* __restrict__ yhe = lds_s + 2 * PS;

    const int tid = threadIdx.x;
    const int gi0 = blockIdx.y * TILE - HOFF;
    const int gj0 = blockIdx.x * TILE - HOFF;
    const bool interior = (gi0 >= 0) && (gj0 >= 0) && (gi0 + R <= H) && (gj0 + R <= W);

    const int t0 = tid, t1 = tid + NT;
    const int i0_ = t0 / CPR, i1_ = t1 / CPR;
    const int b0 = i0_ * S + (t0 - i0_ * CPR) * 8;
    const int b1 = i1_ * S + (t1 - i1_ * CPR) * 8;
    const bool act1 = (t1 < NCH);

    const half8 kTIV  = splat8(TIV);
    const half8 kINVD = splat8(INVD);
    const half8 k15   = splat8(1.5f);
    const half8 kM05  = splat8(-0.5f);

    half8 wh0, wh1, wv0, wv1;   // SIGMA*w (BC-baked)
    half8 ci0, ci1;             // CF*img
    half8 x0, x1;               // primal state
    half8 xt0r, xt1r;           // own-chunk x_tilde (register copy of LDS)
    half8 yh0, yh1, yv0, yv1;   // dual state

    auto loadC = [&](int t, half8& whr, half8& wvr, half8& cir, half8& xr,
                     half8& xtr, half8& yhr, half8& yvr) {
        const int i  = t / CPR;
        const int j0 = (t - i * CPR) * 8;
        const int gi = gi0 + i;
        const int gj = gj0 + j0;
        if (interior) {
            const long o = (long)gi * W + gj;
            const float4* ip = reinterpret_cast<const float4*>(img + o);
            float4 a = ip[0], b = ip[1];
            float im[8] = {a.x, a.y, a.z, a.w, b.x, b.y, b.z, b.w};
            whr = *reinterpret_cast<const half8*>(whp + o);
            wvr = *reinterpret_cast<const half8*>(wvp + o);
#pragma unroll
            for (int k = 0; k < 8; ++k) cir[k] = (_Float16)(CF * im[k]);
            if (PHASE == 0) {
#pragma unroll
                for (int k = 0; k < 8; ++k) xr[k] = (_Float16)im[k];
                xtr = xr;
                yhr = splat8(0.f); yvr = splat8(0.f);
            } else {
                xr  = *reinterpret_cast<const half8*>(xg  + o);
                xtr = *reinterpret_cast<const half8*>(xtg + o);
                yhr = *reinterpret_cast<const half8*>(yhg + o);
                yvr = *reinterpret_cast<const half8*>(yvg + o);
            }
        } else {
            const int gic = min(max(gi, 0), H - 1);
            const bool rowin = (gi >= 0) && (gi < H);
#pragma unroll
            for (int k = 0; k < 8; ++k) {
                const int gjk = gj + k;
                const int gjc = min(max(gjk, 0), W - 1);
                const bool inim = rowin && (gjk >= 0) && (gjk < W);
                const long o = (long)gic * W + gjc;
                const float imf = img[o];
                whr[k] = inim ? whp[o] : (_Float16)0.0f;
                wvr[k] = inim ? wvp[o] : (_Float16)0.0f;
                cir[k] = (_Float16)(CF * imf);
                if (PHASE == 0) {
                    xr[k]  = (_Float16)imf;
                    xtr[k] = (_Float16)imf;
                    yhr[k] = (_Float16)0.0f;
                    yvr[k] = (_Float16)0.0f;
                } else {
                    xr[k]  = xg[o];
                    xtr[k] = xtg[o];
                    yhr[k] = inim ? yhg[o] : (_Float16)0.0f;
                    yvr[k] = inim ? yvg[o] : (_Float16)0.0f;
                }
            }
        }
        *reinterpret_cast<half8*>(xtp + i * S + j0) = xtr;
    };
    loadC(t0, wh0, wv0, ci0, x0, xt0r, yh0, yv0);
    if (act1) loadC(t1, wh1, wv1, ci1, x1, xt1r, yh1, yv1);
    if (tid == 0) yhe[0] = (_Float16)0.0f;
    __syncthreads();

    for (int it = 0; it < 10; ++it) {
        // dual: y = clamp(y + grad(xt)*SIGMA*w); own cv comes from register
        auto dualC = [&](int t, int base, half8 cv, half8 wh, half8 wv,
                         half8& yh, half8& yv) {
            _Float16 rt = xtp[base + 8];
            half8 bv = *reinterpret_cast<const half8*>(xtp + base + S);
            half8 sh = __builtin_shufflevector(cv, cv, 1, 2, 3, 4, 5, 6, 7, 7);
            sh[7] = rt;
            yh = clamp8((sh - cv) * wh + yh);
            yv = clamp8((bv - cv) * wv + yv);
            *reinterpret_cast<half8*>(yvp + base) = yv;
            yhe[t + 1] = yh[7];
        };
        dualC(t0, b0, xt0r, wh0, wv0, yh0, yv0);
        if (act1) dualC(t1, b1, xt1r, wh1, wv1, yh1, yv1);
        __syncthreads();

        // primal: xn = x*INVD + (TIV*dv + ci); xt = 1.5*xn - 0.5*x (reg + LDS)
        auto primC = [&](int t, int base, half8 yh, half8 yv, half8 ci,
                         half8& x, half8& xtr) {
            _Float16 yl = yhe[t];
            half8 yva = *reinterpret_cast<const half8*>(yvp + base - S);
            half8 ysh = __builtin_shufflevector(yh, yh, 0, 0, 1, 2, 3, 4, 5, 6);
            ysh[0] = yl;
            half8 dv = (yh - ysh) + (yv - yva);
            half8 tt = dv * kTIV + ci;
            half8 xn = x * kINVD + tt;
            half8 xt = xn * k15 + x * kM05;
            x = xn;
            xtr = xt;
            *reinterpret_cast<half8*>(xtp + base) = xt;
        };
        primC(t0, b0, yh0, yv0, ci0, x0, xt0r);
        if (act1) primC(t1, b1, yh1, yv1, ci1, x1, xt1r);
        __syncthreads();
    }

    // ---------------- stores ----------------
    const int r  = tid >> 3;           // 0..63
    const int k  = tid & 7;            // 0..7
    const int lb = (HOFF + r) * S + HOFF + k * 8;          // 8B-aligned (two half4)
    const long gb = (long)(blockIdx.y * TILE + r) * W + blockIdx.x * TILE + k * 8;

    if (PHASE == 0) {
        // pass 1: xt (xtp) -> xtg, yv (yvp) -> yvg
        {
            half4v a0 = *reinterpret_cast<const half4v*>(xtp + lb);
            half4v a1 = *reinterpret_cast<const half4v*>(xtp + lb + 4);
            half8 o; o[0]=a0[0];o[1]=a0[1];o[2]=a0[2];o[3]=a0[3];
                     o[4]=a1[0];o[5]=a1[1];o[6]=a1[2];o[7]=a1[3];
            *reinterpret_cast<half8*>(xtg + gb) = o;
            half4v b0v = *reinterpret_cast<const half4v*>(yvp + lb);
            half4v b1v = *reinterpret_cast<const half4v*>(yvp + lb + 4);
            half8 o2; o2[0]=b0v[0];o2[1]=b0v[1];o2[2]=b0v[2];o2[3]=b0v[3];
                      o2[4]=b1v[0];o2[5]=b1v[1];o2[6]=b1v[2];o2[7]=b1v[3];
            *reinterpret_cast<half8*>(yvg + gb) = o2;
        }
        __syncthreads();
        // bounce: x -> xtp, yh -> yvp
        *reinterpret_cast<half8*>(xtp + b0) = x0;
        *reinterpret_cast<half8*>(yvp + b0) = yh0;
        if (act1) {
            *reinterpret_cast<half8*>(xtp + b1) = x1;
            *reinterpret_cast<half8*>(yvp + b1) = yh1;
        }
        __syncthreads();
        // pass 2: x -> xg, yh -> yhg
        {
            half4v a0 = *reinterpret_cast<const half4v*>(xtp + lb);
            half4v a1 = *reinterpret_cast<const half4v*>(xtp + lb + 4);
            half8 o; o[0]=a0[0];o[1]=a0[1];o[2]=a0[2];o[3]=a0[3];
                     o[4]=a1[0];o[5]=a1[1];o[6]=a1[2];o[7]=a1[3];
            *reinterpret_cast<half8*>(xg + gb) = o;
            half4v b0v = *reinterpret_cast<const half4v*>(yvp + lb);
            half4v b1v = *reinterpret_cast<const half4v*>(yvp + lb + 4);
            half8 o2; o2[0]=b0v[0];o2[1]=b0v[1];o2[2]=b0v[2];o2[3]=b0v[3];
                      o2[4]=b1v[0];o2[5]=b1v[1];o2[6]=b1v[2];o2[7]=b1v[3];
            *reinterpret_cast<half8*>(yhg + gb) = o2;
        }
    } else {
        half4v a = *reinterpret_cast<const half4v*>(xtp + lb);
        half4v b = *reinterpret_cast<const half4v*>(xtp + lb + 4);
        float4 o0 = make_float4((float)a[0], (float)a[1], (float)a[2], (float)a[3]);
        float4 o1 = make_float4((float)b[0], (float)b[1], (float)b[2], (float)b[3]);
        *reinterpret_cast<float4*>(out + gb)     = o0;
        *reinterpret_cast<float4*>(out + gb + 4) = o1;
    }
}

extern "C" void kernel_launch(void* const* d_in, const int* in_sizes, int n_in,
                              void* d_out, int out_size, void* d_ws, size_t ws_size,
                              hipStream_t stream) {
    const float* img = (const float*)d_in[0];   // (1,H,W)
    const float* wg  = (const float*)d_in[1];   // (2,H,W)
    float* out = (float*)d_out;

    _Float16* ws16 = (_Float16*)d_ws;           // 6 fp16 planes = 12N bytes
    _Float16* whp = ws16;
    _Float16* wvp = ws16 + N;
    _Float16* xg  = ws16 + 2 * N;
    _Float16* xtg = ws16 + 3 * N;
    _Float16* yhg = ws16 + 4 * N;
    _Float16* yvg = ws16 + 5 * N;

    pack_w<<<dim3((int)(N / 8 / 256)), dim3(256), 0, stream>>>(wg, whp, wvp);

    dim3 grid(W / TILE, H / TILE);              // 64 x 64 = 4096 blocks
    fused_pd<0><<<grid, dim3(NT), 0, stream>>>(img, whp, wvp, xg, xtg, yhg, yvg, out);
    fused_pd<1><<<grid, dim3(NT), 0, stream>>>(img, whp, wvp, xg, xtg, yhg, yvg, out);
}

// Round 14
// 344.594 us; speedup vs baseline: 4.9081x; 1.0719x over previous
//
#include <hip/hip_runtime.h>

static constexpr int H = 4096;
static constexpr int W = 4096;
static constexpr long N = (long)H * W;

static constexpr int TILE = 64;
static constexpr int HOFF = 12;              // halo capacity per phase
static constexpr int R    = TILE + 2*HOFF;   // 88
static constexpr int S    = R;               // row stride (halfs)
static constexpr int PS   = R * S;           // 7744 halfs
static constexpr int CPR  = R / 8;           // 11 chunks per row
static constexpr int NCH  = R * CPR;         // 968 chunk tasks
static constexpr int NT   = 512;             // 8 waves; 4 blocks/CU

static constexpr float SIGMA = 14.285714285714286f;  // 1/(7*0.01)
static constexpr float INVD  = 1.0f / 1.07f;
static constexpr float TIV   = 0.01f / 1.07f;        // TAU/(1+LT)
static constexpr float CF    = 0.07f / 1.07f;        // LAMBDA*TAU/(1+LT)

typedef _Float16 half8  __attribute__((ext_vector_type(8)));
typedef _Float16 half4v __attribute__((ext_vector_type(4)));

__device__ __forceinline__ half8 splat8(float f) {
    _Float16 h = (_Float16)f;
    half8 v = {h, h, h, h, h, h, h, h};
    return v;
}
__device__ __forceinline__ half8 clamp8(half8 v) {
    v = __builtin_elementwise_min(v, splat8(1.0f));
    v = __builtin_elementwise_max(v, splat8(-1.0f));
    return v;
}

// ---------------- pack: whp = SIGMA*w_h (0 at col W-1), wvp = SIGMA*w_v (0 at row H-1)
__global__ __launch_bounds__(256) void pack_w(
    const float* __restrict__ wg, _Float16* __restrict__ whp, _Float16* __restrict__ wvp)
{
    const long p = ((long)blockIdx.x * 256 + threadIdx.x) * 8;
    const int i = (int)(p >> 12);
    const float4* hp = reinterpret_cast<const float4*>(wg + p);
    float4 a = hp[0], b = hp[1];
    const float4* vp = reinterpret_cast<const float4*>(wg + N + p);
    float4 c = vp[0], d = vp[1];
    half8 wh, wv;
    wh[0]=(_Float16)(SIGMA*a.x); wh[1]=(_Float16)(SIGMA*a.y);
    wh[2]=(_Float16)(SIGMA*a.z); wh[3]=(_Float16)(SIGMA*a.w);
    wh[4]=(_Float16)(SIGMA*b.x); wh[5]=(_Float16)(SIGMA*b.y);
    wh[6]=(_Float16)(SIGMA*b.z); wh[7]=(_Float16)(SIGMA*b.w);
    wv[0]=(_Float16)(SIGMA*c.x); wv[1]=(_Float16)(SIGMA*c.y);
    wv[2]=(_Float16)(SIGMA*c.z); wv[3]=(_Float16)(SIGMA*c.w);
    wv[4]=(_Float16)(SIGMA*d.x); wv[5]=(_Float16)(SIGMA*d.y);
    wv[6]=(_Float16)(SIGMA*d.z); wv[7]=(_Float16)(SIGMA*d.w);
    if ((p & 4095) + 8 == W) wh[7] = (_Float16)0.0f;   // gh BC at last col
    if (i == H - 1) wv = splat8(0.0f);                 // gv BC at last row
    *reinterpret_cast<half8*>(whp + p) = wh;
    *reinterpret_cast<half8*>(wvp + p) = wv;
}

// ---------------- phase kernel ----------------
// PHASE 0: iters 0..9 (full) + dual of iter 10; stores center {x, yh, yv}.
// PHASE 1: primal of iter 10 + iters 11..19 (full); stores center xt fp32.
// The mid-iteration cut kills the xt plane (dual-10 consumed it). Own-chunk
// xt kept in registers; LDS: xt plane + yv plane + yh-edge array. BCs
// data-encoded (w=0). Halo invalidates 1 ring/iter; margins: phase0 ends
// y-valid margin 1, phase1 ends margin 2 (>=0). Out-of-range halo reads land
// on finite LDS and feed only cone-invalid pixels (validated rounds 4-13).
template<int PHASE>
__global__ __launch_bounds__(NT, 4) void fused_pd(
    const float* __restrict__ img,
    const _Float16* __restrict__ whp, const _Float16* __restrict__ wvp,
    _Float16* __restrict__ xg, _Float16* __restrict__ yhg, _Float16* __restrict__ yvg,
    float* __restrict__ out)
{
    __shared__ _Float16 lds_s[2 * PS + NCH + 2];   // 34,820 B
    _Float16* __restrict__ xtp = lds_s;
    _Float16* __restrict__ yvp = lds_s + PS;
    _Float16* __restrict__ yhe = lds_s + 2 * PS;

    const int tid = threadIdx.x;
    const int gi0 = blockIdx.y * TILE - HOFF;
    const int gj0 = blockIdx.x * TILE - HOFF;
    const bool interior = (gi0 >= 0) && (gj0 >= 0) && (gi0 + R <= H) && (gj0 + R <= W);

    const int t0 = tid, t1 = tid + NT;
    const int i0_ = t0 / CPR, i1_ = t1 / CPR;
    const int b0 = i0_ * S + (t0 - i0_ * CPR) * 8;
    const int b1 = i1_ * S + (t1 - i1_ * CPR) * 8;
    const bool act1 = (t1 < NCH);

    const half8 kTIV  = splat8(TIV);
    const half8 kINVD = splat8(INVD);
    const half8 k15   = splat8(1.5f);
    const half8 kM05  = splat8(-0.5f);

    half8 wh0, wh1, wv0, wv1;   // SIGMA*w (BC-baked)
    half8 ci0, ci1;             // CF*img
    half8 x0, x1;               // primal state
    half8 xt0r, xt1r;           // own-chunk x_tilde register
    half8 yh0, yh1, yv0, yv1;   // dual state

    auto loadC = [&](int t, half8& whr, half8& wvr, half8& cir, half8& xr,
                     half8& xtr, half8& yhr, half8& yvr) {
        const int i  = t / CPR;
        const int j0 = (t - i * CPR) * 8;
        const int gi = gi0 + i;
        const int gj = gj0 + j0;
        if (interior) {
            const long o = (long)gi * W + gj;
            const float4* ip = reinterpret_cast<const float4*>(img + o);
            float4 a = ip[0], b = ip[1];
            float im[8] = {a.x, a.y, a.z, a.w, b.x, b.y, b.z, b.w};
            whr = *reinterpret_cast<const half8*>(whp + o);
            wvr = *reinterpret_cast<const half8*>(wvp + o);
#pragma unroll
            for (int k = 0; k < 8; ++k) cir[k] = (_Float16)(CF * im[k]);
            if (PHASE == 0) {
#pragma unroll
                for (int k = 0; k < 8; ++k) xr[k] = (_Float16)im[k];
                xtr = xr;
                yhr = splat8(0.f); yvr = splat8(0.f);
            } else {
                xr  = *reinterpret_cast<const half8*>(xg  + o);
                yhr = *reinterpret_cast<const half8*>(yhg + o);
                yvr = *reinterpret_cast<const half8*>(yvg + o);
            }
        } else {
            const int gic = min(max(gi, 0), H - 1);
            const bool rowin = (gi >= 0) && (gi < H);
#pragma unroll
            for (int k = 0; k < 8; ++k) {
                const int gjk = gj + k;
                const int gjc = min(max(gjk, 0), W - 1);
                const bool inim = rowin && (gjk >= 0) && (gjk < W);
                const long o = (long)gic * W + gjc;
                const float imf = img[o];
                whr[k] = inim ? whp[o] : (_Float16)0.0f;
                wvr[k] = inim ? wvp[o] : (_Float16)0.0f;
                cir[k] = (_Float16)(CF * imf);
                if (PHASE == 0) {
                    xr[k]  = (_Float16)imf;
                    xtr[k] = (_Float16)imf;
                    yhr[k] = (_Float16)0.0f;
                    yvr[k] = (_Float16)0.0f;
                } else {
                    xr[k]  = xg[o];
                    yhr[k] = inim ? yhg[o] : (_Float16)0.0f;
                    yvr[k] = inim ? yvg[o] : (_Float16)0.0f;
                }
            }
        }
        const int base = i * S + j0;
        if (PHASE == 0) {
            *reinterpret_cast<half8*>(xtp + base) = xtr;   // xt = img
        } else {
            // primal-first order: seed LDS with yv + yh edge; xtp seeded with
            // x so the row-0 yva out-of-plane read hits finite data.
            *reinterpret_cast<half8*>(xtp + base) = xr;
            *reinterpret_cast<half8*>(yvp + base) = yvr;
            yhe[t + 1] = yhr[7];
        }
    };
    loadC(t0, wh0, wv0, ci0, x0, xt0r, yh0, yv0);
    if (act1) loadC(t1, wh1, wv1, ci1, x1, xt1r, yh1, yv1);
    if (tid == 0) yhe[0] = (_Float16)0.0f;
    __syncthreads();

    // batched dual for both chunks (reads first -> shorter waitcnt chain)
    auto dual_all = [&](bool write_yhe) {
        _Float16 rt0 = xtp[b0 + 8];
        half8 bv0 = *reinterpret_cast<const half8*>(xtp + b0 + S);
        _Float16 rt1 = (_Float16)0.f; half8 bv1;
        if (act1) {
            rt1 = xtp[b1 + 8];
            bv1 = *reinterpret_cast<const half8*>(xtp + b1 + S);
        }
        {
            half8 sh = __builtin_shufflevector(xt0r, xt0r, 1, 2, 3, 4, 5, 6, 7, 7);
            sh[7] = rt0;
            yh0 = clamp8((sh - xt0r) * wh0 + yh0);
            yv0 = clamp8((bv0 - xt0r) * wv0 + yv0);
            *reinterpret_cast<half8*>(yvp + b0) = yv0;
            if (write_yhe) yhe[t0 + 1] = yh0[7];
        }
        if (act1) {
            half8 sh = __builtin_shufflevector(xt1r, xt1r, 1, 2, 3, 4, 5, 6, 7, 7);
            sh[7] = rt1;
            yh1 = clamp8((sh - xt1r) * wh1 + yh1);
            yv1 = clamp8((bv1 - xt1r) * wv1 + yv1);
            *reinterpret_cast<half8*>(yvp + b1) = yv1;
            if (write_yhe) yhe[t1 + 1] = yh1[7];
        }
    };
    // batched primal for both chunks
    auto prim_all = [&]() {
        _Float16 yl0 = yhe[t0];
        half8 yva0 = *reinterpret_cast<const half8*>(yvp + b0 - S);
        _Float16 yl1 = (_Float16)0.f; half8 yva1;
        if (act1) {
            yl1  = yhe[t1];
            yva1 = *reinterpret_cast<const half8*>(yvp + b1 - S);
        }
        {
            half8 ysh = __builtin_shufflevector(yh0, yh0, 0, 0, 1, 2, 3, 4, 5, 6);
            ysh[0] = yl0;
            half8 dv = (yh0 - ysh) + (yv0 - yva0);
            half8 tt = dv * kTIV + ci0;
            half8 xn = x0 * kINVD + tt;
            half8 xt = xn * k15 + x0 * kM05;
            x0 = xn; xt0r = xt;
            *reinterpret_cast<half8*>(xtp + b0) = xt;
        }
        if (act1) {
            half8 ysh = __builtin_shufflevector(yh1, yh1, 0, 0, 1, 2, 3, 4, 5, 6);
            ysh[0] = yl1;
            half8 dv = (yh1 - ysh) + (yv1 - yva1);
            half8 tt = dv * kTIV + ci1;
            half8 xn = x1 * kINVD + tt;
            half8 xt = xn * k15 + x1 * kM05;
            x1 = xn; xt1r = xt;
            *reinterpret_cast<half8*>(xtp + b1) = xt;
        }
    };

    if (PHASE == 1) {          // primal of iter 10 (dual-10 ran in phase0)
        prim_all();
        __syncthreads();
    }
    const int NIT = (PHASE == 0) ? 10 : 9;
    for (int it = 0; it < NIT; ++it) {
        dual_all(true);
        __syncthreads();
        prim_all();
        __syncthreads();
    }
    if (PHASE == 0) {          // dual of iter 10; yhe not needed
        dual_all(false);
        __syncthreads();
    }

    // ---------------- stores ----------------
    const int r  = tid >> 3;           // 0..63
    const int k  = tid & 7;            // 0..7
    const int lb = (HOFF + r) * S + HOFF + k * 8;          // 8B-aligned
    const long gb = (long)(blockIdx.y * TILE + r) * W + blockIdx.x * TILE + k * 8;

    if (PHASE == 0) {
        // pass 1: yv (yvp) -> yvg
        {
            half4v a0 = *reinterpret_cast<const half4v*>(yvp + lb);
            half4v a1 = *reinterpret_cast<const half4v*>(yvp + lb + 4);
            half8 o; o[0]=a0[0];o[1]=a0[1];o[2]=a0[2];o[3]=a0[3];
                     o[4]=a1[0];o[5]=a1[1];o[6]=a1[2];o[7]=a1[3];
            *reinterpret_cast<half8*>(yvg + gb) = o;
        }
        __syncthreads();
        // bounce: x -> xtp, yh -> yvp
        *reinterpret_cast<half8*>(xtp + b0) = x0;
        *reinterpret_cast<half8*>(yvp + b0) = yh0;
        if (act1) {
            *reinterpret_cast<half8*>(xtp + b1) = x1;
            *reinterpret_cast<half8*>(yvp + b1) = yh1;
        }
        __syncthreads();
        // pass 2: x -> xg, yh -> yhg
        {
            half4v a0 = *reinterpret_cast<const half4v*>(xtp + lb);
            half4v a1 = *reinterpret_cast<const half4v*>(xtp + lb + 4);
            half8 o; o[0]=a0[0];o[1]=a0[1];o[2]=a0[2];o[3]=a0[3];
                     o[4]=a1[0];o[5]=a1[1];o[6]=a1[2];o[7]=a1[3];
            *reinterpret_cast<half8*>(xg + gb) = o;
            half4v b0v = *reinterpret_cast<const half4v*>(yvp + lb);
            half4v b1v = *reinterpret_cast<const half4v*>(yvp + lb + 4);
            half8 o2; o2[0]=b0v[0];o2[1]=b0v[1];o2[2]=b0v[2];o2[3]=b0v[3];
                      o2[4]=b1v[0];o2[5]=b1v[1];o2[6]=b1v[2];o2[7]=b1v[3];
            *reinterpret_cast<half8*>(yhg + gb) = o2;
        }
    } else {
        half4v a = *reinterpret_cast<const half4v*>(xtp + lb);
        half4v b = *reinterpret_cast<const half4v*>(xtp + lb + 4);
        float4 o0 = make_float4((float)a[0], (float)a[1], (float)a[2], (float)a[3]);
        float4 o1 = make_float4((float)b[0], (float)b[1], (float)b[2], (float)b[3]);
        *reinterpret_cast<float4*>(out + gb)     = o0;
        *reinterpret_cast<float4*>(out + gb + 4) = o1;
    }
}

extern "C" void kernel_launch(void* const* d_in, const int* in_sizes, int n_in,
                              void* d_out, int out_size, void* d_ws, size_t ws_size,
                              hipStream_t stream) {
    const float* img = (const float*)d_in[0];   // (1,H,W)
    const float* wg  = (const float*)d_in[1];   // (2,H,W)
    float* out = (float*)d_out;

    _Float16* ws16 = (_Float16*)d_ws;           // 5 fp16 planes = 10N bytes
    _Float16* whp = ws16;
    _Float16* wvp = ws16 + N;
    _Float16* xg  = ws16 + 2 * N;
    _Float16* yhg = ws16 + 3 * N;
    _Float16* yvg = ws16 + 4 * N;

    pack_w<<<dim3((int)(N / 8 / 256)), dim3(256), 0, stream>>>(wg, whp, wvp);

    dim3 grid(W / TILE, H / TILE);              // 64 x 64 = 4096 blocks
    fused_pd<0><<<grid, dim3(NT), 0, stream>>>(img, whp, wvp, xg, yhg, yvg, out);
    fused_pd<1><<<grid, dim3(NT), 0, stream>>>(img, whp, wvp, xg, yhg, yvg, out);
}

// Round 15
// 342.276 us; speedup vs baseline: 4.9413x; 1.0068x over previous
//
#include <hip/hip_runtime.h>

static constexpr int H = 4096;
static constexpr int W = 4096;
static constexpr long N = (long)H * W;

static constexpr int TILE = 64;
static constexpr int HOFF = 12;              // halo capacity; 10 needed + 2 slack
static constexpr int R    = TILE + 2*HOFF;   // 88
static constexpr int CPR  = R / 8;           // 11 chunks per row
static constexpr int PR   = R / 2;           // 44 pair-rows
static constexpr int NTASK= PR * CPR;        // 484 tasks (16 px each, rows 2p,2p+1)
static constexpr int PSE  = PR * R;          // 3872 halfs per half-plane
static constexpr int NT   = 512;             // 8 waves; 4 blocks/CU

static constexpr float SIGMA = 14.285714285714286f;  // 1/(7*0.01)
static constexpr float INVD  = 1.0f / 1.07f;
static constexpr float TIV   = 0.01f / 1.07f;        // TAU/(1+LT)
static constexpr float CF    = 0.07f / 1.07f;        // LAMBDA*TAU/(1+LT)

typedef _Float16 half8  __attribute__((ext_vector_type(8)));
typedef _Float16 half4v __attribute__((ext_vector_type(4)));

__device__ __forceinline__ half8 splat8(float f) {
    _Float16 h = (_Float16)f;
    half8 v = {h, h, h, h, h, h, h, h};
    return v;
}
__device__ __forceinline__ half8 clamp8(half8 v) {
    v = __builtin_elementwise_min(v, splat8(1.0f));
    v = __builtin_elementwise_max(v, splat8(-1.0f));
    return v;
}
__device__ __forceinline__ half4v lo4(half8 v) {
    half4v r = {v[0], v[1], v[2], v[3]}; return r;
}
__device__ __forceinline__ half4v hi4(half8 v) {
    half4v r = {v[4], v[5], v[6], v[7]}; return r;
}

// ---------------- pack: whp = SIGMA*w_h (0 at col W-1), wvp = SIGMA*w_v (0 at row H-1)
__global__ __launch_bounds__(256) void pack_w(
    const float* __restrict__ wg, _Float16* __restrict__ whp, _Float16* __restrict__ wvp)
{
    const long p = ((long)blockIdx.x * 256 + threadIdx.x) * 8;
    const int i = (int)(p >> 12);
    const float4* hp = reinterpret_cast<const float4*>(wg + p);
    float4 a = hp[0], b = hp[1];
    const float4* vp = reinterpret_cast<const float4*>(wg + N + p);
    float4 c = vp[0], d = vp[1];
    half8 wh, wv;
    wh[0]=(_Float16)(SIGMA*a.x); wh[1]=(_Float16)(SIGMA*a.y);
    wh[2]=(_Float16)(SIGMA*a.z); wh[3]=(_Float16)(SIGMA*a.w);
    wh[4]=(_Float16)(SIGMA*b.x); wh[5]=(_Float16)(SIGMA*b.y);
    wh[6]=(_Float16)(SIGMA*b.z); wh[7]=(_Float16)(SIGMA*b.w);
    wv[0]=(_Float16)(SIGMA*c.x); wv[1]=(_Float16)(SIGMA*c.y);
    wv[2]=(_Float16)(SIGMA*c.z); wv[3]=(_Float16)(SIGMA*c.w);
    wv[4]=(_Float16)(SIGMA*d.x); wv[5]=(_Float16)(SIGMA*d.y);
    wv[6]=(_Float16)(SIGMA*d.z); wv[7]=(_Float16)(SIGMA*d.w);
    if ((p & 4095) + 8 == W) wh[7] = (_Float16)0.0f;   // gh BC at last col
    if (i == H - 1) wv = splat8(0.0f);                 // gv BC at last row
    *reinterpret_cast<half8*>(whp + p) = wh;
    *reinterpret_cast<half8*>(wvp + p) = wv;
}

// ---------------- phase kernel ----------------
// Vertical pairing: task t owns rows (2p, 2p+1), cols [j0, j0+8).
// In-register reuse: bv(row 2p) = xt1r, yva(row 2p+1) = yv0.
// LDS: even-row xt plane, odd-row yv plane, edge arrays yheA/yheB (yh[7] per
// task) and xteo (odd-row xt[0] per task). 7 LDS ops / 16 px / iter.
// PHASE 0: iters 0..9 + dual of iter 10; stores {x,yh,yv} center from regs.
// PHASE 1: primal of iter 10 + iters 11..19; stores center xt fp32 from regs.
// BCs data-encoded (w=0); all out-of-plane/wrap reads land on finite LDS and
// feed only cone-invalid halo pixels (margins: 12 >= 10+2; validated r4-r14).
template<int PHASE>
__global__ __launch_bounds__(NT, 4) void fused_pd(
    const float* __restrict__ img,
    const _Float16* __restrict__ whp, const _Float16* __restrict__ wvp,
    _Float16* __restrict__ xg, _Float16* __restrict__ yhg, _Float16* __restrict__ yvg,
    float* __restrict__ out)
{
    __shared__ _Float16 lds_s[2 * PSE + 3 * (NTASK + 2)];  // 9202 halfs = 18.4 KB
    _Float16* __restrict__ xte  = lds_s;                   // xt, even rows
    _Float16* __restrict__ yvo  = lds_s + PSE;             // yv, odd rows
    _Float16* __restrict__ yheA = lds_s + 2 * PSE;         // yh[7], row 2p, idx 1+t
    _Float16* __restrict__ yheB = yheA + (NTASK + 2);      // yh[7], row 2p+1
    _Float16* __restrict__ xteo = yheB + (NTASK + 2);      // xt[0], row 2p+1, idx t

    const int tid = threadIdx.x;
    const bool act = tid < NTASK;
    const int t  = act ? tid : 0;
    const int p  = t / CPR;
    const int j0 = (t - p * CPR) * 8;
    const int be = p * R + j0;
    const int gi0 = blockIdx.y * TILE - HOFF;
    const int gj0 = blockIdx.x * TILE - HOFF;
    const bool interior = (gi0 >= 0) && (gj0 >= 0) && (gi0 + R <= H) && (gj0 + R <= W);

    const half8 kTIV  = splat8(TIV);
    const half8 kINVD = splat8(INVD);
    const half8 k15   = splat8(1.5f);
    const half8 kM05  = splat8(-0.5f);

    half8 wh0, wh1, wv0, wv1;   // SIGMA*w rows 2p, 2p+1
    half8 ci0, ci1;             // CF*img
    half8 x0, x1;               // primal state
    half8 xt0r, xt1r;           // own x_tilde
    half8 yh0, yh1, yv0, yv1;   // dual state

    // ---------------- load & seed ----------------
    auto loadRow = [&](int gi, int gj, half8& whr, half8& wvr, half8& cir,
                       half8& xr, half8& yhr, half8& yvr) {
        if (interior) {
            const long o = (long)gi * W + gj;
            const float4* ip = reinterpret_cast<const float4*>(img + o);
            float4 a = ip[0], b = ip[1];
            float im[8] = {a.x, a.y, a.z, a.w, b.x, b.y, b.z, b.w};
            whr = *reinterpret_cast<const half8*>(whp + o);
            wvr = *reinterpret_cast<const half8*>(wvp + o);
#pragma unroll
            for (int k = 0; k < 8; ++k) cir[k] = (_Float16)(CF * im[k]);
            if (PHASE == 0) {
#pragma unroll
                for (int k = 0; k < 8; ++k) xr[k] = (_Float16)im[k];
                yhr = splat8(0.f); yvr = splat8(0.f);
            } else {
                xr  = *reinterpret_cast<const half8*>(xg  + o);
                yhr = *reinterpret_cast<const half8*>(yhg + o);
                yvr = *reinterpret_cast<const half8*>(yvg + o);
            }
        } else {
            const int gic = min(max(gi, 0), H - 1);
            const bool rowin = (gi >= 0) && (gi < H);
#pragma unroll
            for (int k = 0; k < 8; ++k) {
                const int gjk = gj + k;
                const int gjc = min(max(gjk, 0), W - 1);
                const bool inim = rowin && (gjk >= 0) && (gjk < W);
                const long o = (long)gic * W + gjc;
                const float imf = img[o];
                whr[k] = inim ? whp[o] : (_Float16)0.0f;
                wvr[k] = inim ? wvp[o] : (_Float16)0.0f;
                cir[k] = (_Float16)(CF * imf);
                if (PHASE == 0) {
                    xr[k]  = (_Float16)imf;
                    yhr[k] = (_Float16)0.0f;
                    yvr[k] = (_Float16)0.0f;
                } else {
                    xr[k]  = xg[o];
                    yhr[k] = inim ? yhg[o] : (_Float16)0.0f;
                    yvr[k] = inim ? yvg[o] : (_Float16)0.0f;
                }
            }
        }
    };
    if (act) {
        const int gi = gi0 + 2 * p;
        const int gj = gj0 + j0;
        loadRow(gi,     gj, wh0, wv0, ci0, x0, yh0, yv0);
        loadRow(gi + 1, gj, wh1, wv1, ci1, x1, yh1, yv1);
        if (PHASE == 0) {
            xt0r = x0; xt1r = x1;
            *reinterpret_cast<half8*>(xte + be) = xt0r;   // xt = img, even rows
            *reinterpret_cast<half8*>(yvo + be) = splat8(0.f);
            xteo[t] = xt1r[0];
            yheA[1 + t] = (_Float16)0.0f;
            yheB[1 + t] = (_Float16)0.0f;
        } else {
            // primal-first seeds: yv odd rows + yh edges (left-neighbor reads)
            *reinterpret_cast<half8*>(yvo + be) = yv1;
            yheA[1 + t] = yh0[7];
            yheB[1 + t] = yh1[7];
        }
    }
    if (tid == NT - 1) {
        yheA[0] = (_Float16)0.0f;
        yheB[0] = (_Float16)0.0f;
        xteo[NTASK]     = (_Float16)0.0f;
        xteo[NTASK + 1] = (_Float16)0.0f;
    }
    __syncthreads();

    // -------- dual: y = clamp(y + grad(xt)*SIGMA*w) --------
    auto dual_all = [&](bool writes) {
        if (act) {
            _Float16 rt0 = xte[be + 8];       // right neighbor, even row
            _Float16 rt1 = xteo[t + 1];       // right neighbor, odd row (edge)
            half8 bv1 = *reinterpret_cast<const half8*>(xte + be + R);  // row 2p+2
            half8 sh0 = __builtin_shufflevector(xt0r, xt0r, 1, 2, 3, 4, 5, 6, 7, 7);
            sh0[7] = rt0;
            half8 sh1 = __builtin_shufflevector(xt1r, xt1r, 1, 2, 3, 4, 5, 6, 7, 7);
            sh1[7] = rt1;
            yh0 = clamp8((sh0 - xt0r) * wh0 + yh0);
            yv0 = clamp8((xt1r - xt0r) * wv0 + yv0);    // bv(2p) = xt1r (reg)
            yh1 = clamp8((sh1 - xt1r) * wh1 + yh1);
            yv1 = clamp8((bv1 - xt1r) * wv1 + yv1);
            if (writes) {
                *reinterpret_cast<half8*>(yvo + be) = yv1;
                yheA[1 + t] = yh0[7];
                yheB[1 + t] = yh1[7];
            }
        }
    };
    // -------- primal: xn = x*INVD + (TIV*dv + ci); xt = 1.5*xn - 0.5*x --------
    auto prim_all = [&](bool writes) {
        if (act) {
            _Float16 yl0 = yheA[t];
            _Float16 yl1 = yheB[t];
            half8 yva0 = *reinterpret_cast<const half8*>(yvo + be - R);  // row 2p-1
            half8 ysh0 = __builtin_shufflevector(yh0, yh0, 0, 0, 1, 2, 3, 4, 5, 6);
            ysh0[0] = yl0;
            half8 ysh1 = __builtin_shufflevector(yh1, yh1, 0, 0, 1, 2, 3, 4, 5, 6);
            ysh1[0] = yl1;
            half8 dv0 = (yh0 - ysh0) + (yv0 - yva0);
            half8 dv1 = (yh1 - ysh1) + (yv1 - yv0);     // yva(2p+1) = yv0 (reg)
            half8 tt0 = dv0 * kTIV + ci0;
            half8 xn0 = x0 * kINVD + tt0;
            half8 xtn0 = xn0 * k15 + x0 * kM05;
            x0 = xn0; xt0r = xtn0;
            half8 tt1 = dv1 * kTIV + ci1;
            half8 xn1 = x1 * kINVD + tt1;
            half8 xtn1 = xn1 * k15 + x1 * kM05;
            x1 = xn1; xt1r = xtn1;
            if (writes) {
                *reinterpret_cast<half8*>(xte + be) = xt0r;
                xteo[t] = xt1r[0];
            }
        }
    };

    if (PHASE == 1) {            // primal of iter 10 (dual-10 ran in phase0)
        prim_all(true);
        __syncthreads();
    }
    const int NIT = (PHASE == 0) ? 10 : 9;
    for (int it = 0; it < NIT; ++it) {
        dual_all(true);
        __syncthreads();
        prim_all(!(PHASE == 1 && it == NIT - 1));
        __syncthreads();
    }
    if (PHASE == 0) {            // dual of iter 10; no consumers -> no LDS writes
        dual_all(false);
    }

    // ---------------- stores (direct from registers) ----------------
    // center rows: p in [6,38); center cols intersect chunk:
    //   j0==8 -> elems 4..7; 16<=j0<=64 -> full; j0==72 -> elems 0..3.
    if (act && p >= 6 && p < 38 && j0 >= 8 && j0 <= 72) {
        const long g0 = (long)(gi0 + 2 * p) * W + (gj0 + j0);
        const long g1 = g0 + W;
        if (PHASE == 0) {
            if (j0 >= 16 && j0 <= 64) {
                *reinterpret_cast<half8*>(xg  + g0) = x0;
                *reinterpret_cast<half8*>(xg  + g1) = x1;
                *reinterpret_cast<half8*>(yhg + g0) = yh0;
                *reinterpret_cast<half8*>(yhg + g1) = yh1;
                *reinterpret_cast<half8*>(yvg + g0) = yv0;
                *reinterpret_cast<half8*>(yvg + g1) = yv1;
            } else if (j0 == 8) {
                *reinterpret_cast<half4v*>(xg  + g0 + 4) = hi4(x0);
                *reinterpret_cast<half4v*>(xg  + g1 + 4) = hi4(x1);
                *reinterpret_cast<half4v*>(yhg + g0 + 4) = hi4(yh0);
                *reinterpret_cast<half4v*>(yhg + g1 + 4) = hi4(yh1);
                *reinterpret_cast<half4v*>(yvg + g0 + 4) = hi4(yv0);
                *reinterpret_cast<half4v*>(yvg + g1 + 4) = hi4(yv1);
            } else {  // j0 == 72
                *reinterpret_cast<half4v*>(xg  + g0) = lo4(x0);
                *reinterpret_cast<half4v*>(xg  + g1) = lo4(x1);
                *reinterpret_cast<half4v*>(yhg + g0) = lo4(yh0);
                *reinterpret_cast<half4v*>(yhg + g1) = lo4(yh1);
                *reinterpret_cast<half4v*>(yvg + g0) = lo4(yv0);
                *reinterpret_cast<half4v*>(yvg + g1) = lo4(yv1);
            }
        } else {
            float4 a0 = make_float4((float)xt0r[0], (float)xt0r[1], (float)xt0r[2], (float)xt0r[3]);
            float4 a1 = make_float4((float)xt0r[4], (float)xt0r[5], (float)xt0r[6], (float)xt0r[7]);
            float4 b0 = make_float4((float)xt1r[0], (float)xt1r[1], (float)xt1r[2], (float)xt1r[3]);
            float4 b1 = make_float4((float)xt1r[4], (float)xt1r[5], (float)xt1r[6], (float)xt1r[7]);
            if (j0 >= 16 && j0 <= 64) {
                *reinterpret_cast<float4*>(out + g0)     = a0;
                *reinterpret_cast<float4*>(out + g0 + 4) = a1;
                *reinterpret_cast<float4*>(out + g1)     = b0;
                *reinterpret_cast<float4*>(out + g1 + 4) = b1;
            } else if (j0 == 8) {
                *reinterpret_cast<float4*>(out + g0 + 4) = a1;
                *reinterpret_cast<float4*>(out + g1 + 4) = b1;
            } else {  // j0 == 72
                *reinterpret_cast<float4*>(out + g0) = a0;
                *reinterpret_cast<float4*>(out + g1) = b0;
            }
        }
    }
}

extern "C" void kernel_launch(void* const* d_in, const int* in_sizes, int n_in,
                              void* d_out, int out_size, void* d_ws, size_t ws_size,
                              hipStream_t stream) {
    const float* img = (const float*)d_in[0];   // (1,H,W)
    const float* wg  = (const float*)d_in[1];   // (2,H,W)
    float* out = (float*)d_out;

    _Float16* ws16 = (_Float16*)d_ws;           // 5 fp16 planes = 10N bytes
    _Float16* whp = ws16;
    _Float16* wvp = ws16 + N;
    _Float16* xg  = ws16 + 2 * N;
    _Float16* yhg = ws16 + 3 * N;
    _Float16* yvg = ws16 + 4 * N;

    pack_w<<<dim3((int)(N / 8 / 256)), dim3(256), 0, stream>>>(wg, whp, wvp);

    dim3 grid(W / TILE, H / TILE);              // 64 x 64 = 4096 blocks
    fused_pd<0><<<grid, dim3(NT), 0, stream>>>(img, whp, wvp, xg, yhg, yvg, out);
    fused_pd<1><<<grid, dim3(NT), 0, stream>>>(img, whp, wvp, xg, yhg, yvg, out);
}